// Round 1
// baseline (4667.051 us; speedup 1.0000x reference)
//
#include <hip/hip_runtime.h>

#define N 100000
#define E 1000000
#define ETOT 1100000   // E + N self-loops

__device__ __forceinline__ float lrelu(float x) { return x > 0.f ? x : 0.2f * x; }

// monotone float<->uint mapping so atomicMax(uint) == float max; key 0 == -inf
__device__ __forceinline__ unsigned f2o(float f) {
    unsigned u = __float_as_uint(f);
    return (u & 0x80000000u) ? ~u : (u | 0x80000000u);
}
__device__ __forceinline__ float o2f(unsigned u) {
    return __uint_as_float((u & 0x80000000u) ? (u & 0x7FFFFFFFu) : ~u);
}

// ---------------- layer 1: h1 = x0 @ W1  (100000x128 @ 128x256) ----------------
#define G1_ROWS 16
__global__ __launch_bounds__(256) void gemm1_kernel(const float* __restrict__ x0,
                                                    const float* __restrict__ W1,
                                                    float* __restrict__ h1) {
    __shared__ float xs[G1_ROWS][128];   // 8 KB
    const int t = threadIdx.x;           // column c = t (0..255)
    const int row0 = blockIdx.x * G1_ROWS;
    // stage 16 rows of x0 (2048 floats) via float4
    const float4* xsrc = (const float4*)(x0 + (size_t)row0 * 128);
    float4* xd = (float4*)(&xs[0][0]);
    for (int i = t; i < G1_ROWS * 128 / 4; i += 256) xd[i] = xsrc[i];
    __syncthreads();
    float acc[G1_ROWS];
#pragma unroll
    for (int r = 0; r < G1_ROWS; r++) acc[r] = 0.f;
#pragma unroll 4
    for (int k = 0; k < 128; k++) {
        float w = W1[k * 256 + t];
#pragma unroll
        for (int r = 0; r < G1_ROWS; r++) acc[r] += xs[r][k] * w;
    }
#pragma unroll
    for (int r = 0; r < G1_ROWS; r++) h1[(size_t)(row0 + r) * 256 + t] = acc[r];
}

// ---------------- attention logits: a_src1/a_dst1 [N,8] ----------------
__global__ __launch_bounds__(256) void att1_kernel(const float* __restrict__ h1,
                                                   const float* __restrict__ att_src,
                                                   const float* __restrict__ att_dst,
                                                   float* __restrict__ a_src,
                                                   float* __restrict__ a_dst) {
    const int wid = (blockIdx.x * 256 + threadIdx.x) >> 6;   // node = wave id
    const int lane = threadIdx.x & 63;
    float4 hv = ((const float4*)(h1 + (size_t)wid * 256))[lane];
    float4 as = ((const float4*)att_src)[lane];
    float4 ad = ((const float4*)att_dst)[lane];
    float ps = hv.x * as.x + hv.y * as.y + hv.z * as.z + hv.w * as.w;
    float pd = hv.x * ad.x + hv.y * ad.y + hv.z * ad.z + hv.w * ad.w;
    // reduce within 8-lane groups (each group = one head: elements 4l..4l+3)
#pragma unroll
    for (int off = 1; off < 8; off <<= 1) {
        ps += __shfl_xor(ps, off, 64);
        pd += __shfl_xor(pd, off, 64);
    }
    if ((lane & 7) == 0) {
        int h = lane >> 3;
        a_src[wid * 8 + h] = ps;
        a_dst[wid * 8 + h] = pd;
    }
}

// ---------------- edge segment-max (layer 1) ----------------
__global__ __launch_bounds__(256) void edgemax1_kernel(const int* __restrict__ ei,
                                                       const float* __restrict__ a_src,
                                                       const float* __restrict__ a_dst,
                                                       unsigned* __restrict__ m1) {
    const int e = blockIdx.x * 256 + threadIdx.x;
    if (e >= ETOT) return;
    int s, d;
    if (e < E) { s = ei[e]; d = ei[E + e]; } else { s = d = e - E; }
    float4 s0 = ((const float4*)(a_src + (size_t)s * 8))[0];
    float4 s1 = ((const float4*)(a_src + (size_t)s * 8))[1];
    float4 d0 = ((const float4*)(a_dst + (size_t)d * 8))[0];
    float4 d1 = ((const float4*)(a_dst + (size_t)d * 8))[1];
    float al[8] = {lrelu(s0.x + d0.x), lrelu(s0.y + d0.y), lrelu(s0.z + d0.z), lrelu(s0.w + d0.w),
                   lrelu(s1.x + d1.x), lrelu(s1.y + d1.y), lrelu(s1.z + d1.z), lrelu(s1.w + d1.w)};
#pragma unroll
    for (int h = 0; h < 8; h++) atomicMax(&m1[(size_t)d * 8 + h], f2o(al[h]));
}

// ---------------- edge exp + scatter accumulate (layer 1): one wave per edge ----------------
__global__ __launch_bounds__(256) void edgeacc1_kernel(const int* __restrict__ ei,
                                                       const float* __restrict__ a_src,
                                                       const float* __restrict__ a_dst,
                                                       const unsigned* __restrict__ m1,
                                                       const float* __restrict__ h1,
                                                       float* __restrict__ acc1,
                                                       float* __restrict__ denom1) {
    const int e = (blockIdx.x * 256 + threadIdx.x) >> 6;  // wave id = edge
    const int lane = threadIdx.x & 63;
    int s, d;
    if (e < E) { s = ei[e]; d = ei[E + e]; } else { s = d = e - E; }
    const int h = lane >> 3;   // head of this lane's 4 elements
    float alpha = lrelu(a_src[(size_t)s * 8 + h] + a_dst[(size_t)d * 8 + h]);
    float m = o2f(m1[(size_t)d * 8 + h]);
    float ea = __expf(alpha - m);
    float4 hv = ((const float4*)(h1 + (size_t)s * 256))[lane];
    float* dp = acc1 + (size_t)d * 256 + lane * 4;
    atomicAdd(dp + 0, ea * hv.x);
    atomicAdd(dp + 1, ea * hv.y);
    atomicAdd(dp + 2, ea * hv.z);
    atomicAdd(dp + 3, ea * hv.w);
    if ((lane & 7) == 0) atomicAdd(&denom1[(size_t)d * 8 + h], ea);
}

// ---------------- normalize + bias + relu (in place: acc1 -> x2) ----------------
__global__ __launch_bounds__(256) void norm1_kernel(float* __restrict__ acc1,
                                                    const float* __restrict__ denom1,
                                                    const float* __restrict__ b1) {
    const int i4 = blockIdx.x * 256 + threadIdx.x;  // over N*64 float4s
    const int n = i4 >> 6;
    const int q = i4 & 63;            // float4 index in row; head = q>>3
    float dn = denom1[n * 8 + (q >> 3)];
    float4 v = ((float4*)acc1)[i4];
    float4 bb = ((const float4*)b1)[q];
    float inv = 1.0f / dn;
    v.x = v.x * inv + bb.x; v.y = v.y * inv + bb.y;
    v.z = v.z * inv + bb.z; v.w = v.w * inv + bb.w;
    v.x = v.x > 0.f ? v.x : 0.f; v.y = v.y > 0.f ? v.y : 0.f;
    v.z = v.z > 0.f ? v.z : 0.f; v.w = v.w > 0.f ? v.w : 0.f;
    ((float4*)acc1)[i4] = v;
}

// ---------------- layer 2 GEMM: h2 = x2 @ W2 (256->32), fused att logits ----------------
__global__ __launch_bounds__(256) void gemm2_kernel(const float* __restrict__ x2,
                                                    const float* __restrict__ W2,
                                                    const float* __restrict__ att_src2,
                                                    const float* __restrict__ att_dst2,
                                                    float* __restrict__ h2,
                                                    float* __restrict__ a_src2,
                                                    float* __restrict__ a_dst2) {
    __shared__ float w2s[256 * 32];   // 32 KB
    const int t = threadIdx.x;
    for (int i = t; i < 256 * 32 / 4; i += 256) ((float4*)w2s)[i] = ((const float4*)W2)[i];
    __syncthreads();
    const int c = t & 31;
    const int rsub = t >> 5;          // 0..7
    const float asv = att_src2[c], adv = att_dst2[c];
    const int base = blockIdx.x * 32;
    for (int it = 0; it < 4; it++) {
        const int n = base + it * 8 + rsub;
        const float4* xr = (const float4*)(x2 + (size_t)n * 256);
        float acc = 0.f;
#pragma unroll 8
        for (int k4 = 0; k4 < 64; k4++) {
            float4 xv = xr[k4];
            acc += xv.x * w2s[(k4 * 4 + 0) * 32 + c] + xv.y * w2s[(k4 * 4 + 1) * 32 + c] +
                   xv.z * w2s[(k4 * 4 + 2) * 32 + c] + xv.w * w2s[(k4 * 4 + 3) * 32 + c];
        }
        h2[(size_t)n * 32 + c] = acc;
        float ps = acc * asv, pd = acc * adv;
#pragma unroll
        for (int off = 1; off < 32; off <<= 1) {
            ps += __shfl_xor(ps, off, 64);
            pd += __shfl_xor(pd, off, 64);
        }
        if (c == 0) { a_src2[n] = ps; a_dst2[n] = pd; }
    }
}

// ---------------- edge segment-max (layer 2) ----------------
__global__ __launch_bounds__(256) void edgemax2_kernel(const int* __restrict__ ei,
                                                       const float* __restrict__ a_src2,
                                                       const float* __restrict__ a_dst2,
                                                       unsigned* __restrict__ m2) {
    const int e = blockIdx.x * 256 + threadIdx.x;
    if (e >= ETOT) return;
    int s, d;
    if (e < E) { s = ei[e]; d = ei[E + e]; } else { s = d = e - E; }
    atomicMax(&m2[d], f2o(lrelu(a_src2[s] + a_dst2[d])));
}

// ---------------- edge exp + scatter (layer 2): half-wave per edge ----------------
__global__ __launch_bounds__(256) void edgeacc2_kernel(const int* __restrict__ ei,
                                                       const float* __restrict__ a_src2,
                                                       const float* __restrict__ a_dst2,
                                                       const unsigned* __restrict__ m2,
                                                       const float* __restrict__ h2,
                                                       float* __restrict__ acc2,
                                                       float* __restrict__ denom2) {
    const int e = (blockIdx.x * 256 + threadIdx.x) >> 5;
    const int lane = threadIdx.x & 31;
    int s, d;
    if (e < E) { s = ei[e]; d = ei[E + e]; } else { s = d = e - E; }
    float alpha = lrelu(a_src2[s] + a_dst2[d]);
    float ea = __expf(alpha - o2f(m2[d]));
    float hv = h2[(size_t)s * 32 + lane];
    atomicAdd(&acc2[(size_t)d * 32 + lane], ea * hv);
    if (lane == 0) atomicAdd(&denom2[d], ea);
}

// ---------------- final: normalize layer-2 + linear 32->40 ----------------
__global__ __launch_bounds__(256) void final_kernel(const float* __restrict__ acc2,
                                                    const float* __restrict__ denom2,
                                                    const float* __restrict__ b2,
                                                    const float* __restrict__ linW,
                                                    const float* __restrict__ linb,
                                                    float* __restrict__ out) {
    __shared__ float lws[32 * 40];
    __shared__ float vbuf[4][32];
    const int t = threadIdx.x;
    for (int i = t; i < 1280; i += 256) lws[i] = linW[i];
    const int w = t >> 6, lane = t & 63;
    const int n = blockIdx.x * 4 + w;
    if (lane < 32) vbuf[w][lane] = acc2[(size_t)n * 32 + lane] / denom2[n] + b2[lane];
    __syncthreads();
    if (lane < 40) {
        float acc = linb[lane];
#pragma unroll
        for (int c = 0; c < 32; c++) acc += vbuf[w][c] * lws[c * 40 + lane];
        out[(size_t)n * 40 + lane] = acc;
    }
}

extern "C" void kernel_launch(void* const* d_in, const int* in_sizes, int n_in,
                              void* d_out, int out_size, void* d_ws, size_t ws_size,
                              hipStream_t stream) {
    const float* x0       = (const float*)d_in[0];
    const float* W1       = (const float*)d_in[1];
    const float* att_src1 = (const float*)d_in[2];
    const float* att_dst1 = (const float*)d_in[3];
    const float* b1       = (const float*)d_in[4];
    const float* W2       = (const float*)d_in[5];
    const float* att_src2 = (const float*)d_in[6];
    const float* att_dst2 = (const float*)d_in[7];
    const float* b2       = (const float*)d_in[8];
    const float* linW     = (const float*)d_in[9];
    const float* linb     = (const float*)d_in[10];
    const int*   ei       = (const int*)d_in[11];
    float* out = (float*)d_out;
    float* ws  = (float*)d_ws;

    // workspace layout (floats); total 61.2M floats = 244.8 MB
    float*    h1      = ws;                      // 25.6M
    float*    a_src1  = ws + 25600000;           // 0.8M
    float*    a_dst1  = ws + 26400000;           // 0.8M
    float*    acc1    = ws + 27200000;           // 25.6M  (zero region start)
    float*    denom1  = ws + 52800000;           // 0.8M
    unsigned* m1      = (unsigned*)(ws + 53600000); // 0.8M
    float*    acc2    = ws + 54400000;           // 3.2M
    float*    denom2  = ws + 57600000;           // 0.1M
    unsigned* m2      = (unsigned*)(ws + 57700000); // 0.1M (zero region end)
    float*    h2      = ws + 57800000;           // 3.2M
    float*    a_src2  = ws + 61000000;           // 0.1M
    float*    a_dst2  = ws + 61100000;           // 0.1M

    // zero accumulators + max-keys (key 0 == -inf) in one memset: 30.6M floats
    hipMemsetAsync(acc1, 0, 30600000ull * 4, stream);

    gemm1_kernel<<<N / G1_ROWS, 256, 0, stream>>>(x0, W1, h1);
    att1_kernel<<<N / 4, 256, 0, stream>>>(h1, att_src1, att_dst1, a_src1, a_dst1);
    edgemax1_kernel<<<(ETOT + 255) / 256, 256, 0, stream>>>(ei, a_src1, a_dst1, m1);
    edgeacc1_kernel<<<ETOT / 4, 256, 0, stream>>>(ei, a_src1, a_dst1, m1, h1, acc1, denom1);
    norm1_kernel<<<N * 64 / 256, 256, 0, stream>>>(acc1, denom1, b1);
    gemm2_kernel<<<N / 32, 256, 0, stream>>>(acc1, W2, att_src2, att_dst2, h2, a_src2, a_dst2);
    edgemax2_kernel<<<(ETOT + 255) / 256, 256, 0, stream>>>(ei, a_src2, a_dst2, m2);
    edgeacc2_kernel<<<ETOT / 8, 256, 0, stream>>>(ei, a_src2, a_dst2, m2, h2, acc2, denom2);
    final_kernel<<<N / 4, 256, 0, stream>>>(acc2, denom2, b2, linW, linb, out);
}

// Round 2
// 727.495 us; speedup vs baseline: 6.4152x; 6.4152x over previous
//
#include <hip/hip_runtime.h>

#define N 100000
#define E 1000000
#define ETOT 1100000   // E + N self-loops
#define NB1 391        // ceil(N/256)

__device__ __forceinline__ float lrelu(float x) { return x > 0.f ? x : 0.2f * x; }

// ---------------- CSR build: histogram ----------------
__global__ __launch_bounds__(256) void hist_kernel(const int* __restrict__ ei,
                                                   int* __restrict__ hist) {
    const int e = blockIdx.x * 256 + threadIdx.x;
    if (e >= ETOT) return;
    int d = (e < E) ? ei[E + e] : (e - E);
    atomicAdd(&hist[d], 1);
}

// block-local exclusive scan of hist -> rofs, block totals -> bsum
__global__ __launch_bounds__(256) void scan1_kernel(const int* __restrict__ hist,
                                                    int* __restrict__ rofs,
                                                    int* __restrict__ bsum) {
    __shared__ int sm[256];
    const int t = threadIdx.x;
    const int i = blockIdx.x * 256 + t;
    int v = (i < N) ? hist[i] : 0;
    sm[t] = v;
    __syncthreads();
#pragma unroll
    for (int off = 1; off < 256; off <<= 1) {
        int x = (t >= off) ? sm[t - off] : 0;
        __syncthreads();
        sm[t] += x;
        __syncthreads();
    }
    if (i < N) rofs[i] = sm[t] - v;           // exclusive
    if (t == 255) bsum[blockIdx.x] = sm[255]; // block total
}

// single-block exclusive scan of the 391 block sums
__global__ __launch_bounds__(512) void scan2_kernel(int* __restrict__ bsum) {
    __shared__ int sm[512];
    const int t = threadIdx.x;
    int v = (t < NB1) ? bsum[t] : 0;
    sm[t] = v;
    __syncthreads();
#pragma unroll
    for (int off = 1; off < 512; off <<= 1) {
        int x = (t >= off) ? sm[t - off] : 0;
        __syncthreads();
        sm[t] += x;
        __syncthreads();
    }
    if (t < NB1) bsum[t] = sm[t] - v;
}

// add block offsets; produce final rofs and a cursor copy for the scatter
__global__ __launch_bounds__(256) void scan3_kernel(int* __restrict__ rofs,
                                                    const int* __restrict__ bsum,
                                                    int* __restrict__ cursor) {
    const int i = blockIdx.x * 256 + threadIdx.x;
    if (i < N) {
        int r = rofs[i] + bsum[blockIdx.x];
        rofs[i] = r;
        cursor[i] = r;
    }
    if (i == 0) rofs[N] = ETOT;
}

// scatter src indices into dst-sorted order
__global__ __launch_bounds__(256) void scatter_kernel(const int* __restrict__ ei,
                                                      int* __restrict__ cursor,
                                                      int* __restrict__ esrc) {
    const int e = blockIdx.x * 256 + threadIdx.x;
    if (e >= ETOT) return;
    int s, d;
    if (e < E) { s = ei[e]; d = ei[E + e]; } else { s = d = e - E; }
    int pos = atomicAdd(&cursor[d], 1);
    esrc[pos] = s;
}

// ---------------- layer 1: h1 = x0 @ W1  (100000x128 @ 128x256) ----------------
#define G1_ROWS 16
__global__ __launch_bounds__(256) void gemm1_kernel(const float* __restrict__ x0,
                                                    const float* __restrict__ W1,
                                                    float* __restrict__ h1) {
    __shared__ float xs[G1_ROWS][128];   // 8 KB
    const int t = threadIdx.x;           // column c = t (0..255)
    const int row0 = blockIdx.x * G1_ROWS;
    const float4* xsrc = (const float4*)(x0 + (size_t)row0 * 128);
    float4* xd = (float4*)(&xs[0][0]);
    for (int i = t; i < G1_ROWS * 128 / 4; i += 256) xd[i] = xsrc[i];
    __syncthreads();
    float acc[G1_ROWS];
#pragma unroll
    for (int r = 0; r < G1_ROWS; r++) acc[r] = 0.f;
#pragma unroll 4
    for (int k = 0; k < 128; k++) {
        float w = W1[k * 256 + t];
#pragma unroll
        for (int r = 0; r < G1_ROWS; r++) acc[r] += xs[r][k] * w;
    }
#pragma unroll
    for (int r = 0; r < G1_ROWS; r++) h1[(size_t)(row0 + r) * 256 + t] = acc[r];
}

// ---------------- attention logits: a_src1/a_dst1 [N,8] ----------------
__global__ __launch_bounds__(256) void att1_kernel(const float* __restrict__ h1,
                                                   const float* __restrict__ att_src,
                                                   const float* __restrict__ att_dst,
                                                   float* __restrict__ a_src,
                                                   float* __restrict__ a_dst) {
    const int wid = (blockIdx.x * 256 + threadIdx.x) >> 6;   // node = wave id
    const int lane = threadIdx.x & 63;
    float4 hv = ((const float4*)(h1 + (size_t)wid * 256))[lane];
    float4 as = ((const float4*)att_src)[lane];
    float4 ad = ((const float4*)att_dst)[lane];
    float ps = hv.x * as.x + hv.y * as.y + hv.z * as.z + hv.w * as.w;
    float pd = hv.x * ad.x + hv.y * ad.y + hv.z * ad.z + hv.w * ad.w;
#pragma unroll
    for (int off = 1; off < 8; off <<= 1) {
        ps += __shfl_xor(ps, off, 64);
        pd += __shfl_xor(pd, off, 64);
    }
    if ((lane & 7) == 0) {
        int h = lane >> 3;
        a_src[wid * 8 + h] = ps;
        a_dst[wid * 8 + h] = pd;
    }
}

// ---------------- layer 1 segmented softmax-aggregate: one wave per node ----------------
// online softmax over this node's incoming edges; acc held in registers; no atomics.
__global__ __launch_bounds__(256) void seg1_kernel(const int* __restrict__ esrc,
                                                   const int* __restrict__ rofs,
                                                   const float* __restrict__ a_src,
                                                   const float* __restrict__ a_dst,
                                                   const float* __restrict__ h1,
                                                   const float* __restrict__ b1,
                                                   float* __restrict__ x2) {
    const int n = (blockIdx.x * 256 + threadIdx.x) >> 6;   // node = wave id
    const int lane = threadIdx.x & 63;
    const int h = lane >> 3;                               // head of this lane's float4
    if (n >= N) return;
    const int rs = rofs[n], re = rofs[n + 1];
    const float ad = a_dst[(size_t)n * 8 + h];
    float m = -1e30f, den = 0.f;
    float4 acc = {0.f, 0.f, 0.f, 0.f};
    for (int j = rs; j < re; j++) {
        const int s = esrc[j];
        float alpha = lrelu(a_src[(size_t)s * 8 + h] + ad);
        float mn = fmaxf(m, alpha);
        float sc = __expf(m - mn);
        float ea = __expf(alpha - mn);
        float4 hv = ((const float4*)(h1 + (size_t)s * 256))[lane];
        den = den * sc + ea;
        acc.x = acc.x * sc + ea * hv.x;
        acc.y = acc.y * sc + ea * hv.y;
        acc.z = acc.z * sc + ea * hv.z;
        acc.w = acc.w * sc + ea * hv.w;
        m = mn;
    }
    const float inv = 1.0f / den;
    float4 bb = ((const float4*)b1)[lane];
    float4 v;
    v.x = acc.x * inv + bb.x; v.y = acc.y * inv + bb.y;
    v.z = acc.z * inv + bb.z; v.w = acc.w * inv + bb.w;
    v.x = v.x > 0.f ? v.x : 0.f; v.y = v.y > 0.f ? v.y : 0.f;
    v.z = v.z > 0.f ? v.z : 0.f; v.w = v.w > 0.f ? v.w : 0.f;
    ((float4*)(x2 + (size_t)n * 256))[lane] = v;
}

// ---------------- layer 2 GEMM: h2 = x2 @ W2 (256->32), fused att logits ----------------
__global__ __launch_bounds__(256) void gemm2_kernel(const float* __restrict__ x2,
                                                    const float* __restrict__ W2,
                                                    const float* __restrict__ att_src2,
                                                    const float* __restrict__ att_dst2,
                                                    float* __restrict__ h2,
                                                    float* __restrict__ a_src2,
                                                    float* __restrict__ a_dst2) {
    __shared__ float w2s[256 * 32];   // 32 KB
    const int t = threadIdx.x;
    for (int i = t; i < 256 * 32 / 4; i += 256) ((float4*)w2s)[i] = ((const float4*)W2)[i];
    __syncthreads();
    const int c = t & 31;
    const int rsub = t >> 5;          // 0..7
    const float asv = att_src2[c], adv = att_dst2[c];
    const int base = blockIdx.x * 32;
    for (int it = 0; it < 4; it++) {
        const int n = base + it * 8 + rsub;
        const float4* xr = (const float4*)(x2 + (size_t)n * 256);
        float acc = 0.f;
#pragma unroll 8
        for (int k4 = 0; k4 < 64; k4++) {
            float4 xv = xr[k4];
            acc += xv.x * w2s[(k4 * 4 + 0) * 32 + c] + xv.y * w2s[(k4 * 4 + 1) * 32 + c] +
                   xv.z * w2s[(k4 * 4 + 2) * 32 + c] + xv.w * w2s[(k4 * 4 + 3) * 32 + c];
        }
        h2[(size_t)n * 32 + c] = acc;
        float ps = acc * asv, pd = acc * adv;
#pragma unroll
        for (int off = 1; off < 32; off <<= 1) {
            ps += __shfl_xor(ps, off, 64);
            pd += __shfl_xor(pd, off, 64);
        }
        if (c == 0) { a_src2[n] = ps; a_dst2[n] = pd; }
    }
}

// ---------------- layer 2 segmented softmax-aggregate: half-wave per node ----------------
__global__ __launch_bounds__(256) void seg2_kernel(const int* __restrict__ esrc,
                                                   const int* __restrict__ rofs,
                                                   const float* __restrict__ a_src2,
                                                   const float* __restrict__ a_dst2,
                                                   const float* __restrict__ h2,
                                                   const float* __restrict__ b2,
                                                   float* __restrict__ v2) {
    const int n = (blockIdx.x * 256 + threadIdx.x) >> 5;   // node = half-wave id
    const int c = threadIdx.x & 31;
    if (n >= N) return;
    const int rs = rofs[n], re = rofs[n + 1];
    const float ad = a_dst2[n];
    float m = -1e30f, den = 0.f, acc = 0.f;
    for (int j = rs; j < re; j++) {
        const int s = esrc[j];
        float alpha = lrelu(a_src2[s] + ad);
        float mn = fmaxf(m, alpha);
        float sc = __expf(m - mn);
        float ea = __expf(alpha - mn);
        float hv = h2[(size_t)s * 32 + c];
        den = den * sc + ea;
        acc = acc * sc + ea * hv;
        m = mn;
    }
    v2[(size_t)n * 32 + c] = acc / den + b2[c];
}

// ---------------- final: linear 32->40 ----------------
__global__ __launch_bounds__(256) void final_kernel(const float* __restrict__ v2,
                                                    const float* __restrict__ linW,
                                                    const float* __restrict__ linb,
                                                    float* __restrict__ out) {
    __shared__ float lws[32 * 40];
    __shared__ float vbuf[4][32];
    const int t = threadIdx.x;
    for (int i = t; i < 1280; i += 256) lws[i] = linW[i];
    const int w = t >> 6, lane = t & 63;
    const int n = blockIdx.x * 4 + w;
    if (lane < 32) vbuf[w][lane] = v2[(size_t)n * 32 + lane];
    __syncthreads();
    if (lane < 40) {
        float acc = linb[lane];
#pragma unroll
        for (int c = 0; c < 32; c++) acc += vbuf[w][c] * lws[c * 40 + lane];
        out[(size_t)n * 40 + lane] = acc;
    }
}

extern "C" void kernel_launch(void* const* d_in, const int* in_sizes, int n_in,
                              void* d_out, int out_size, void* d_ws, size_t ws_size,
                              hipStream_t stream) {
    const float* x0       = (const float*)d_in[0];
    const float* W1       = (const float*)d_in[1];
    const float* att_src1 = (const float*)d_in[2];
    const float* att_dst1 = (const float*)d_in[3];
    const float* b1       = (const float*)d_in[4];
    const float* W2       = (const float*)d_in[5];
    const float* att_src2 = (const float*)d_in[6];
    const float* att_dst2 = (const float*)d_in[7];
    const float* b2       = (const float*)d_in[8];
    const float* linW     = (const float*)d_in[9];
    const float* linb     = (const float*)d_in[10];
    const int*   ei       = (const int*)d_in[11];
    float* out = (float*)d_out;
    float* ws  = (float*)d_ws;

    // workspace layout (floats); total ~60.9M floats = 243.5 MB
    float* h1      = ws;                        // 25.6M
    float* x2      = ws + 25600000;             // 25.6M
    float* a_src1  = ws + 51200000;             // 0.8M
    float* a_dst1  = ws + 52000000;             // 0.8M
    float* h2      = ws + 52800000;             // 3.2M
    float* v2      = ws + 56000000;             // 3.2M
    float* a_src2  = ws + 59200000;             // 0.1M
    float* a_dst2  = ws + 59300000;             // 0.1M
    int*   hist    = (int*)(ws + 59400000);     // 0.1M
    int*   rofs    = (int*)(ws + 59500000);     // 0.11M (N+1)
    int*   cursor  = (int*)(ws + 59610000);     // 0.1M
    int*   bsum    = (int*)(ws + 59710000);     // 512
    int*   esrc    = (int*)(ws + 59711000);     // 1.1M

    // zero only the histogram (400 KB)
    hipMemsetAsync(hist, 0, (size_t)N * 4, stream);

    // CSR build (dst-sorted edges); shared by both layers
    hist_kernel<<<(ETOT + 255) / 256, 256, 0, stream>>>(ei, hist);
    scan1_kernel<<<NB1, 256, 0, stream>>>(hist, rofs, bsum);
    scan2_kernel<<<1, 512, 0, stream>>>(bsum);
    scan3_kernel<<<NB1, 256, 0, stream>>>(rofs, bsum, cursor);
    scatter_kernel<<<(ETOT + 255) / 256, 256, 0, stream>>>(ei, cursor, esrc);

    gemm1_kernel<<<N / G1_ROWS, 256, 0, stream>>>(x0, W1, h1);
    att1_kernel<<<N / 4, 256, 0, stream>>>(h1, att_src1, att_dst1, a_src1, a_dst1);
    seg1_kernel<<<N / 4, 256, 0, stream>>>(esrc, rofs, a_src1, a_dst1, h1, b1, x2);
    gemm2_kernel<<<N / 32, 256, 0, stream>>>(x2, W2, att_src2, att_dst2, h2, a_src2, a_dst2);
    seg2_kernel<<<N / 8, 256, 0, stream>>>(esrc, rofs, a_src2, a_dst2, h2, b2, v2);
    final_kernel<<<N / 4, 256, 0, stream>>>(v2, linW, linb, out);
}

// Round 3
// 588.436 us; speedup vs baseline: 7.9313x; 1.2363x over previous
//
#include <hip/hip_runtime.h>

#define N 100000
#define E 1000000
#define ETOT 1100000   // E + N self-loops
#define NB1 391        // ceil(N/256)

typedef __attribute__((ext_vector_type(8))) short bf16x8;
typedef __attribute__((ext_vector_type(4))) float f32x4;

__device__ __forceinline__ float lrelu(float x) { return x > 0.f ? x : 0.2f * x; }
// f32 -> bf16 bits, round-to-nearest-even
__device__ __forceinline__ unsigned short f2b(float x) {
    unsigned u = __float_as_uint(x);
    return (unsigned short)((u + 0x7FFFu + ((u >> 16) & 1u)) >> 16);
}
__device__ __forceinline__ float b2f(unsigned short v) {
    return __uint_as_float(((unsigned)v) << 16);
}

// ---------------- CSR build: histogram ----------------
__global__ __launch_bounds__(256) void hist_kernel(const int* __restrict__ ei,
                                                   int* __restrict__ hist) {
    const int e = blockIdx.x * 256 + threadIdx.x;
    if (e >= ETOT) return;
    int d = (e < E) ? ei[E + e] : (e - E);
    atomicAdd(&hist[d], 1);
}

__global__ __launch_bounds__(256) void scan1_kernel(const int* __restrict__ hist,
                                                    int* __restrict__ rofs,
                                                    int* __restrict__ bsum) {
    __shared__ int sm[256];
    const int t = threadIdx.x;
    const int i = blockIdx.x * 256 + t;
    int v = (i < N) ? hist[i] : 0;
    sm[t] = v;
    __syncthreads();
#pragma unroll
    for (int off = 1; off < 256; off <<= 1) {
        int x = (t >= off) ? sm[t - off] : 0;
        __syncthreads();
        sm[t] += x;
        __syncthreads();
    }
    if (i < N) rofs[i] = sm[t] - v;
    if (t == 255) bsum[blockIdx.x] = sm[255];
}

__global__ __launch_bounds__(512) void scan2_kernel(int* __restrict__ bsum) {
    __shared__ int sm[512];
    const int t = threadIdx.x;
    int v = (t < NB1) ? bsum[t] : 0;
    sm[t] = v;
    __syncthreads();
#pragma unroll
    for (int off = 1; off < 512; off <<= 1) {
        int x = (t >= off) ? sm[t - off] : 0;
        __syncthreads();
        sm[t] += x;
        __syncthreads();
    }
    if (t < NB1) bsum[t] = sm[t] - v;
}

__global__ __launch_bounds__(256) void scan3_kernel(int* __restrict__ rofs,
                                                    const int* __restrict__ bsum,
                                                    int* __restrict__ cursor) {
    const int i = blockIdx.x * 256 + threadIdx.x;
    if (i < N) {
        int r = rofs[i] + bsum[blockIdx.x];
        rofs[i] = r;
        cursor[i] = r;
    }
    if (i == 0) rofs[N] = ETOT;
}

__global__ __launch_bounds__(256) void scatter_kernel(const int* __restrict__ ei,
                                                      int* __restrict__ cursor,
                                                      int* __restrict__ esrc) {
    const int e = blockIdx.x * 256 + threadIdx.x;
    if (e >= ETOT) return;
    int s, d;
    if (e < E) { s = ei[e]; d = ei[E + e]; } else { s = d = e - E; }
    int pos = atomicAdd(&cursor[d], 1);
    esrc[pos] = s;
}

// ---------------- W1 -> W1T bf16 [256][128] ----------------
__global__ __launch_bounds__(256) void w1t_kernel(const float* __restrict__ W1,
                                                  unsigned short* __restrict__ W1T) {
    const int k = blockIdx.x;       // 0..127
    const int n = threadIdx.x;      // 0..255
    W1T[(size_t)n * 128 + k] = f2b(W1[(size_t)k * 256 + n]);
}

// ---------------- layer 1 GEMM via MFMA bf16: h1 = x0 @ W1, h1 stored bf16 ----------------
// block = 4 waves; wave computes 32 rows x 256 cols; grid = ceil(N/128) = 782
__global__ __launch_bounds__(256) void gemm1_kernel(const float* __restrict__ x0,
                                                    const unsigned short* __restrict__ W1T,
                                                    unsigned short* __restrict__ h1) {
    const int wv = threadIdx.x >> 6;
    const int lane = threadIdx.x & 63;
    const int quad = lane >> 4, c = lane & 15;
    const int base_m = blockIdx.x * 128 + wv * 32;
    // a-frags: A[m=lane&15][k=quad*8+j], f32 -> bf16 in-register
    bf16x8 af[2][4];
#pragma unroll
    for (int mt = 0; mt < 2; mt++) {
        int row = base_m + mt * 16 + c;
        int rowc = row < N ? row : N - 1;      // clamp loads; stores are guarded
        const float* ap = x0 + (size_t)rowc * 128 + quad * 8;
#pragma unroll
        for (int ks = 0; ks < 4; ks++) {
            float4 lo = *(const float4*)(ap + ks * 32);
            float4 hi = *(const float4*)(ap + ks * 32 + 4);
            bf16x8 f;
            f[0] = (short)f2b(lo.x); f[1] = (short)f2b(lo.y);
            f[2] = (short)f2b(lo.z); f[3] = (short)f2b(lo.w);
            f[4] = (short)f2b(hi.x); f[5] = (short)f2b(hi.y);
            f[6] = (short)f2b(hi.z); f[7] = (short)f2b(hi.w);
            af[mt][ks] = f;
        }
    }
    for (int nt = 0; nt < 16; nt++) {
        f32x4 acc0 = {0.f, 0.f, 0.f, 0.f};
        f32x4 acc1 = {0.f, 0.f, 0.f, 0.f};
#pragma unroll
        for (int ks = 0; ks < 4; ks++) {
            // B[n=lane&15][k=quad*8+j] from W1T[n][k]
            bf16x8 bf = *(const bf16x8*)(W1T + (size_t)(nt * 16 + c) * 128 + ks * 32 + quad * 8);
            acc0 = __builtin_amdgcn_mfma_f32_16x16x32_bf16(af[0][ks], bf, acc0, 0, 0, 0);
            acc1 = __builtin_amdgcn_mfma_f32_16x16x32_bf16(af[1][ks], bf, acc1, 0, 0, 0);
        }
        const int col = nt * 16 + c;
        // D: col=lane&15, row=quad*4+reg
#pragma unroll
        for (int r = 0; r < 4; r++) {
            int row0 = base_m + quad * 4 + r;
            if (row0 < N) h1[(size_t)row0 * 256 + col] = f2b(acc0[r]);
            int row1 = base_m + 16 + quad * 4 + r;
            if (row1 < N) h1[(size_t)row1 * 256 + col] = f2b(acc1[r]);
        }
    }
}

// ---------------- attention logits: a_src1/a_dst1 [N,8] from bf16 h1 ----------------
__global__ __launch_bounds__(256) void att1_kernel(const unsigned short* __restrict__ h1,
                                                   const float* __restrict__ att_src,
                                                   const float* __restrict__ att_dst,
                                                   float* __restrict__ a_src,
                                                   float* __restrict__ a_dst) {
    const int wid = (blockIdx.x * 256 + threadIdx.x) >> 6;   // node = wave id
    const int lane = threadIdx.x & 63;
    ushort4 hb = ((const ushort4*)(h1 + (size_t)wid * 256))[lane];
    float4 hv = {b2f(hb.x), b2f(hb.y), b2f(hb.z), b2f(hb.w)};
    float4 as = ((const float4*)att_src)[lane];
    float4 ad = ((const float4*)att_dst)[lane];
    float ps = hv.x * as.x + hv.y * as.y + hv.z * as.z + hv.w * as.w;
    float pd = hv.x * ad.x + hv.y * ad.y + hv.z * ad.z + hv.w * ad.w;
#pragma unroll
    for (int off = 1; off < 8; off <<= 1) {
        ps += __shfl_xor(ps, off, 64);
        pd += __shfl_xor(pd, off, 64);
    }
    if ((lane & 7) == 0) {
        int h = lane >> 3;
        a_src[wid * 8 + h] = ps;
        a_dst[wid * 8 + h] = pd;
    }
}

// ---------------- layer 1 segmented softmax-aggregate: one wave per node ----------------
__global__ __launch_bounds__(256) void seg1_kernel(const int* __restrict__ esrc,
                                                   const int* __restrict__ rofs,
                                                   const float* __restrict__ a_src,
                                                   const float* __restrict__ a_dst,
                                                   const unsigned short* __restrict__ h1,
                                                   const float* __restrict__ b1,
                                                   unsigned short* __restrict__ x2) {
    const int n = (blockIdx.x * 256 + threadIdx.x) >> 6;   // node = wave id
    const int lane = threadIdx.x & 63;
    const int h = lane >> 3;                               // head of this lane's 4 elems
    if (n >= N) return;
    const int rs = rofs[n], re = rofs[n + 1];
    const float ad = a_dst[(size_t)n * 8 + h];
    float m = -1e30f, den = 0.f;
    float4 acc = {0.f, 0.f, 0.f, 0.f};
    for (int j = rs; j < re; j++) {
        const int s = esrc[j];
        float alpha = lrelu(a_src[(size_t)s * 8 + h] + ad);
        float mn = fmaxf(m, alpha);
        float sc = __expf(m - mn);
        float ea = __expf(alpha - mn);
        ushort4 hb = ((const ushort4*)(h1 + (size_t)s * 256))[lane];
        den = den * sc + ea;
        acc.x = acc.x * sc + ea * b2f(hb.x);
        acc.y = acc.y * sc + ea * b2f(hb.y);
        acc.z = acc.z * sc + ea * b2f(hb.z);
        acc.w = acc.w * sc + ea * b2f(hb.w);
        m = mn;
    }
    const float inv = 1.0f / den;
    float4 bb = ((const float4*)b1)[lane];
    float vx = acc.x * inv + bb.x, vy = acc.y * inv + bb.y;
    float vz = acc.z * inv + bb.z, vw = acc.w * inv + bb.w;
    vx = vx > 0.f ? vx : 0.f; vy = vy > 0.f ? vy : 0.f;
    vz = vz > 0.f ? vz : 0.f; vw = vw > 0.f ? vw : 0.f;
    ushort4 o = {f2b(vx), f2b(vy), f2b(vz), f2b(vw)};
    ((ushort4*)(x2 + (size_t)n * 256))[lane] = o;
}

// ---------------- layer 2 GEMM: h2 = x2 @ W2 (256->32) bf16 in/out, fused att logits ----------------
__global__ __launch_bounds__(256) void gemm2_kernel(const unsigned short* __restrict__ x2,
                                                    const float* __restrict__ W2,
                                                    const float* __restrict__ att_src2,
                                                    const float* __restrict__ att_dst2,
                                                    unsigned short* __restrict__ h2,
                                                    float* __restrict__ a_src2,
                                                    float* __restrict__ a_dst2) {
    __shared__ float w2s[256 * 32];   // 32 KB
    const int t = threadIdx.x;
    for (int i = t; i < 256 * 32 / 4; i += 256) ((float4*)w2s)[i] = ((const float4*)W2)[i];
    __syncthreads();
    const int c = t & 31;
    const int rsub = t >> 5;          // 0..7
    const float asv = att_src2[c], adv = att_dst2[c];
    const int base = blockIdx.x * 32;
    for (int it = 0; it < 4; it++) {
        const int n = base + it * 8 + rsub;
        const ushort4* xr = (const ushort4*)(x2 + (size_t)n * 256);
        float acc = 0.f;
#pragma unroll 8
        for (int k4 = 0; k4 < 64; k4++) {
            ushort4 xb = xr[k4];
            acc += b2f(xb.x) * w2s[(k4 * 4 + 0) * 32 + c] + b2f(xb.y) * w2s[(k4 * 4 + 1) * 32 + c] +
                   b2f(xb.z) * w2s[(k4 * 4 + 2) * 32 + c] + b2f(xb.w) * w2s[(k4 * 4 + 3) * 32 + c];
        }
        h2[(size_t)n * 32 + c] = f2b(acc);
        float ps = acc * asv, pd = acc * adv;
#pragma unroll
        for (int off = 1; off < 32; off <<= 1) {
            ps += __shfl_xor(ps, off, 64);
            pd += __shfl_xor(pd, off, 64);
        }
        if (c == 0) { a_src2[n] = ps; a_dst2[n] = pd; }
    }
}

// ---------------- layer 2 segmented softmax-aggregate: half-wave per node ----------------
__global__ __launch_bounds__(256) void seg2_kernel(const int* __restrict__ esrc,
                                                   const int* __restrict__ rofs,
                                                   const float* __restrict__ a_src2,
                                                   const float* __restrict__ a_dst2,
                                                   const unsigned short* __restrict__ h2,
                                                   const float* __restrict__ b2,
                                                   float* __restrict__ v2) {
    const int n = (blockIdx.x * 256 + threadIdx.x) >> 5;   // node = half-wave id
    const int c = threadIdx.x & 31;
    if (n >= N) return;
    const int rs = rofs[n], re = rofs[n + 1];
    const float ad = a_dst2[n];
    float m = -1e30f, den = 0.f, acc = 0.f;
    for (int j = rs; j < re; j++) {
        const int s = esrc[j];
        float alpha = lrelu(a_src2[s] + ad);
        float mn = fmaxf(m, alpha);
        float sc = __expf(m - mn);
        float ea = __expf(alpha - mn);
        float hv = b2f(h2[(size_t)s * 32 + c]);
        den = den * sc + ea;
        acc = acc * sc + ea * hv;
        m = mn;
    }
    v2[(size_t)n * 32 + c] = acc / den + b2[c];
}

// ---------------- final: linear 32->40 ----------------
__global__ __launch_bounds__(256) void final_kernel(const float* __restrict__ v2,
                                                    const float* __restrict__ linW,
                                                    const float* __restrict__ linb,
                                                    float* __restrict__ out) {
    __shared__ float lws[32 * 40];
    __shared__ float vbuf[4][32];
    const int t = threadIdx.x;
    for (int i = t; i < 1280; i += 256) lws[i] = linW[i];
    const int w = t >> 6, lane = t & 63;
    const int n = blockIdx.x * 4 + w;
    if (lane < 32) vbuf[w][lane] = v2[(size_t)n * 32 + lane];
    __syncthreads();
    if (lane < 40) {
        float acc = linb[lane];
#pragma unroll
        for (int c = 0; c < 32; c++) acc += vbuf[w][c] * lws[c * 40 + lane];
        out[(size_t)n * 40 + lane] = acc;
    }
}

extern "C" void kernel_launch(void* const* d_in, const int* in_sizes, int n_in,
                              void* d_out, int out_size, void* d_ws, size_t ws_size,
                              hipStream_t stream) {
    const float* x0       = (const float*)d_in[0];
    const float* W1       = (const float*)d_in[1];
    const float* att_src1 = (const float*)d_in[2];
    const float* att_dst1 = (const float*)d_in[3];
    const float* b1       = (const float*)d_in[4];
    const float* W2       = (const float*)d_in[5];
    const float* att_src2 = (const float*)d_in[6];
    const float* att_dst2 = (const float*)d_in[7];
    const float* b2       = (const float*)d_in[8];
    const float* linW     = (const float*)d_in[9];
    const float* linb     = (const float*)d_in[10];
    const int*   ei       = (const int*)d_in[11];
    float* out = (float*)d_out;
    float* ws  = (float*)d_ws;

    // workspace layout (float offsets); total ~33.7M floats = 135 MB
    unsigned short* h1  = (unsigned short*)ws;                  // 25.6M bf16 = 12.8M floats
    unsigned short* x2  = (unsigned short*)(ws + 12800000);     // 25.6M bf16
    float* a_src1       = ws + 25600000;                        // 0.8M
    float* a_dst1       = ws + 26400000;                        // 0.8M
    unsigned short* h2  = (unsigned short*)(ws + 27200000);     // 3.2M bf16
    float* v2           = ws + 28800000;                        // 3.2M
    float* a_src2       = ws + 32000000;                        // 0.1M
    float* a_dst2       = ws + 32100000;                        // 0.1M
    unsigned short* W1T = (unsigned short*)(ws + 32200000);     // 32768 bf16
    int*   hist         = (int*)(ws + 32220000);                // 0.1M
    int*   rofs         = (int*)(ws + 32320000);                // N+1
    int*   cursor       = (int*)(ws + 32430000);                // 0.1M
    int*   bsum         = (int*)(ws + 32530000);                // 512
    int*   esrc         = (int*)(ws + 32531000);                // 1.1M

    hipMemsetAsync(hist, 0, (size_t)N * 4, stream);

    // CSR build (dst-sorted edges); shared by both layers
    hist_kernel<<<(ETOT + 255) / 256, 256, 0, stream>>>(ei, hist);
    scan1_kernel<<<NB1, 256, 0, stream>>>(hist, rofs, bsum);
    scan2_kernel<<<1, 512, 0, stream>>>(bsum);
    scan3_kernel<<<NB1, 256, 0, stream>>>(rofs, bsum, cursor);
    scatter_kernel<<<(ETOT + 255) / 256, 256, 0, stream>>>(ei, cursor, esrc);

    w1t_kernel<<<128, 256, 0, stream>>>(W1, W1T);
    gemm1_kernel<<<(N + 127) / 128, 256, 0, stream>>>(x0, W1T, h1);
    att1_kernel<<<N / 4, 256, 0, stream>>>(h1, att_src1, att_dst1, a_src1, a_dst1);
    seg1_kernel<<<N / 4, 256, 0, stream>>>(esrc, rofs, a_src1, a_dst1, h1, b1, x2);
    gemm2_kernel<<<N / 32, 256, 0, stream>>>(x2, W2, att_src2, att_dst2, h2, a_src2, a_dst2);
    seg2_kernel<<<N / 8, 256, 0, stream>>>(esrc, rofs, a_src2, a_dst2, h2, b2, v2);
    final_kernel<<<N / 4, 256, 0, stream>>>(v2, linW, linb, out);
}

// Round 4
// 473.717 us; speedup vs baseline: 9.8520x; 1.2422x over previous
//
#include <hip/hip_runtime.h>

#define N 100000
#define E 1000000
#define ETOT 1100000   // E + N self-loops
#define NB1 391        // ceil(N/256)

typedef __attribute__((ext_vector_type(8))) short bf16x8;
typedef __attribute__((ext_vector_type(4))) float f32x4;

__device__ __forceinline__ float lrelu(float x) { return x > 0.f ? x : 0.2f * x; }
// f32 -> bf16 bits, round-to-nearest-even
__device__ __forceinline__ unsigned short f2b(float x) {
    unsigned u = __float_as_uint(x);
    return (unsigned short)((u + 0x7FFFu + ((u >> 16) & 1u)) >> 16);
}
__device__ __forceinline__ float b2f(unsigned short v) {
    return __uint_as_float(((unsigned)v) << 16);
}

// ---------------- CSR build ----------------
__global__ __launch_bounds__(256) void hist_kernel(const int* __restrict__ ei,
                                                   int* __restrict__ hist) {
    const int e = blockIdx.x * 256 + threadIdx.x;
    if (e >= ETOT) return;
    int d = (e < E) ? ei[E + e] : (e - E);
    atomicAdd(&hist[d], 1);
}

__global__ __launch_bounds__(256) void scan1_kernel(const int* __restrict__ hist,
                                                    int* __restrict__ rofs,
                                                    int* __restrict__ bsum) {
    __shared__ int sm[256];
    const int t = threadIdx.x;
    const int i = blockIdx.x * 256 + t;
    int v = (i < N) ? hist[i] : 0;
    sm[t] = v;
    __syncthreads();
#pragma unroll
    for (int off = 1; off < 256; off <<= 1) {
        int x = (t >= off) ? sm[t - off] : 0;
        __syncthreads();
        sm[t] += x;
        __syncthreads();
    }
    if (i < N) rofs[i] = sm[t] - v;
    if (t == 255) bsum[blockIdx.x] = sm[255];
}

__global__ __launch_bounds__(512) void scan2_kernel(int* __restrict__ bsum) {
    __shared__ int sm[512];
    const int t = threadIdx.x;
    int v = (t < NB1) ? bsum[t] : 0;
    sm[t] = v;
    __syncthreads();
#pragma unroll
    for (int off = 1; off < 512; off <<= 1) {
        int x = (t >= off) ? sm[t - off] : 0;
        __syncthreads();
        sm[t] += x;
        __syncthreads();
    }
    if (t < NB1) bsum[t] = sm[t] - v;
}

__global__ __launch_bounds__(256) void scan3_kernel(int* __restrict__ rofs,
                                                    const int* __restrict__ bsum,
                                                    int* __restrict__ cursor) {
    const int i = blockIdx.x * 256 + threadIdx.x;
    if (i < N) {
        int r = rofs[i] + bsum[blockIdx.x];
        rofs[i] = r;
        cursor[i] = r;
    }
    if (i == 0) rofs[N] = ETOT;
}

__global__ __launch_bounds__(256) void scatter_kernel(const int* __restrict__ ei,
                                                      int* __restrict__ cursor,
                                                      int* __restrict__ esrc) {
    const int e = blockIdx.x * 256 + threadIdx.x;
    if (e >= ETOT) return;
    int s, d;
    if (e < E) { s = ei[e]; d = ei[E + e]; } else { s = d = e - E; }
    int pos = atomicAdd(&cursor[d], 1);
    esrc[pos] = s;
}

// ---------------- weight transposes (bf16) ----------------
__global__ __launch_bounds__(256) void w1t_kernel(const float* __restrict__ W1,
                                                  unsigned short* __restrict__ W1T) {
    const int k = blockIdx.x;       // 0..127
    const int n = threadIdx.x;      // 0..255
    W1T[(size_t)n * 128 + k] = f2b(W1[(size_t)k * 256 + n]);
}
__global__ __launch_bounds__(256) void w2t_kernel(const float* __restrict__ W2,
                                                  unsigned short* __restrict__ W2T) {
    const int n = blockIdx.x;       // 0..31
    const int k = threadIdx.x;      // 0..255
    W2T[(size_t)n * 256 + k] = f2b(W2[(size_t)k * 32 + n]);
}

// ---------------- layer 1 GEMM via MFMA bf16: h1 = x0 @ W1, h1 stored bf16 ----------------
__global__ __launch_bounds__(256) void gemm1_kernel(const float* __restrict__ x0,
                                                    const unsigned short* __restrict__ W1T,
                                                    unsigned short* __restrict__ h1) {
    const int wv = threadIdx.x >> 6;
    const int lane = threadIdx.x & 63;
    const int quad = lane >> 4, c = lane & 15;
    const int base_m = blockIdx.x * 128 + wv * 32;
    bf16x8 af[2][4];
#pragma unroll
    for (int mt = 0; mt < 2; mt++) {
        int row = base_m + mt * 16 + c;
        int rowc = row < N ? row : N - 1;
        const float* ap = x0 + (size_t)rowc * 128 + quad * 8;
#pragma unroll
        for (int ks = 0; ks < 4; ks++) {
            float4 lo = *(const float4*)(ap + ks * 32);
            float4 hi = *(const float4*)(ap + ks * 32 + 4);
            bf16x8 f;
            f[0] = (short)f2b(lo.x); f[1] = (short)f2b(lo.y);
            f[2] = (short)f2b(lo.z); f[3] = (short)f2b(lo.w);
            f[4] = (short)f2b(hi.x); f[5] = (short)f2b(hi.y);
            f[6] = (short)f2b(hi.z); f[7] = (short)f2b(hi.w);
            af[mt][ks] = f;
        }
    }
    for (int nt = 0; nt < 16; nt++) {
        f32x4 acc0 = {0.f, 0.f, 0.f, 0.f};
        f32x4 acc1 = {0.f, 0.f, 0.f, 0.f};
#pragma unroll
        for (int ks = 0; ks < 4; ks++) {
            bf16x8 bf = *(const bf16x8*)(W1T + (size_t)(nt * 16 + c) * 128 + ks * 32 + quad * 8);
            acc0 = __builtin_amdgcn_mfma_f32_16x16x32_bf16(af[0][ks], bf, acc0, 0, 0, 0);
            acc1 = __builtin_amdgcn_mfma_f32_16x16x32_bf16(af[1][ks], bf, acc1, 0, 0, 0);
        }
        const int col = nt * 16 + c;
#pragma unroll
        for (int r = 0; r < 4; r++) {
            int row0 = base_m + quad * 4 + r;
            if (row0 < N) h1[(size_t)row0 * 256 + col] = f2b(acc0[r]);
            int row1 = base_m + 16 + quad * 4 + r;
            if (row1 < N) h1[(size_t)row1 * 256 + col] = f2b(acc1[r]);
        }
    }
}

// ---------------- attention logits: a_src1/a_dst1 [N,8] from bf16 h1 ----------------
__global__ __launch_bounds__(256) void att1_kernel(const unsigned short* __restrict__ h1,
                                                   const float* __restrict__ att_src,
                                                   const float* __restrict__ att_dst,
                                                   float* __restrict__ a_src,
                                                   float* __restrict__ a_dst) {
    const int wid = (blockIdx.x * 256 + threadIdx.x) >> 6;
    const int lane = threadIdx.x & 63;
    ushort4 hb = ((const ushort4*)(h1 + (size_t)wid * 256))[lane];
    float4 hv = {b2f(hb.x), b2f(hb.y), b2f(hb.z), b2f(hb.w)};
    float4 as = ((const float4*)att_src)[lane];
    float4 ad = ((const float4*)att_dst)[lane];
    float ps = hv.x * as.x + hv.y * as.y + hv.z * as.z + hv.w * as.w;
    float pd = hv.x * ad.x + hv.y * ad.y + hv.z * ad.z + hv.w * ad.w;
#pragma unroll
    for (int off = 1; off < 8; off <<= 1) {
        ps += __shfl_xor(ps, off, 64);
        pd += __shfl_xor(pd, off, 64);
    }
    if ((lane & 7) == 0) {
        int h = lane >> 3;
        a_src[wid * 8 + h] = ps;
        a_dst[wid * 8 + h] = pd;
    }
}

// ---------------- layer 1 segmented softmax-aggregate: one wave per node, 4 chains ----------------
#define CH_UPD(K)                                                        \
    {                                                                    \
        float mn = fmaxf(m##K, al##K);                                   \
        float sc = __expf(m##K - mn);                                    \
        float ea = __expf(al##K - mn);                                   \
        d##K = d##K * sc + ea;                                           \
        A##K.x = A##K.x * sc + ea * b2f(hb##K.x);                        \
        A##K.y = A##K.y * sc + ea * b2f(hb##K.y);                        \
        A##K.z = A##K.z * sc + ea * b2f(hb##K.z);                        \
        A##K.w = A##K.w * sc + ea * b2f(hb##K.w);                        \
        m##K = mn;                                                       \
    }

__global__ __launch_bounds__(256) void seg1_kernel(const int* __restrict__ esrc,
                                                   const int* __restrict__ rofs,
                                                   const float* __restrict__ a_src,
                                                   const float* __restrict__ a_dst,
                                                   const unsigned short* __restrict__ h1,
                                                   const float* __restrict__ b1,
                                                   unsigned short* __restrict__ x2) {
    const int n = (blockIdx.x * 256 + threadIdx.x) >> 6;
    const int lane = threadIdx.x & 63;
    const int h = lane >> 3;
    if (n >= N) return;
    const int rs = rofs[n], re = rofs[n + 1];
    const float ad = a_dst[(size_t)n * 8 + h];
    float m0 = -1e30f, m1 = -1e30f, m2 = -1e30f, m3 = -1e30f;
    float d0 = 0.f, d1 = 0.f, d2 = 0.f, d3 = 0.f;
    float4 A0 = {0, 0, 0, 0}, A1 = {0, 0, 0, 0}, A2 = {0, 0, 0, 0}, A3 = {0, 0, 0, 0};
    int j = rs;
    for (; j + 4 <= re; j += 4) {
        int s0 = esrc[j], s1 = esrc[j + 1], s2 = esrc[j + 2], s3 = esrc[j + 3];
        ushort4 hb0 = ((const ushort4*)(h1 + (size_t)s0 * 256))[lane];
        ushort4 hb1 = ((const ushort4*)(h1 + (size_t)s1 * 256))[lane];
        ushort4 hb2 = ((const ushort4*)(h1 + (size_t)s2 * 256))[lane];
        ushort4 hb3 = ((const ushort4*)(h1 + (size_t)s3 * 256))[lane];
        float al0 = lrelu(a_src[(size_t)s0 * 8 + h] + ad);
        float al1 = lrelu(a_src[(size_t)s1 * 8 + h] + ad);
        float al2 = lrelu(a_src[(size_t)s2 * 8 + h] + ad);
        float al3 = lrelu(a_src[(size_t)s3 * 8 + h] + ad);
        CH_UPD(0) CH_UPD(1) CH_UPD(2) CH_UPD(3)
    }
    for (; j < re; j++) {
        int s0 = esrc[j];
        ushort4 hb0 = ((const ushort4*)(h1 + (size_t)s0 * 256))[lane];
        float al0 = lrelu(a_src[(size_t)s0 * 8 + h] + ad);
        CH_UPD(0)
    }
    // merge 4 online-softmax states
    float M = fmaxf(fmaxf(m0, m1), fmaxf(m2, m3));
    float s0 = __expf(m0 - M), s1 = __expf(m1 - M), s2 = __expf(m2 - M), s3 = __expf(m3 - M);
    float den = d0 * s0 + d1 * s1 + d2 * s2 + d3 * s3;
    float4 acc;
    acc.x = A0.x * s0 + A1.x * s1 + A2.x * s2 + A3.x * s3;
    acc.y = A0.y * s0 + A1.y * s1 + A2.y * s2 + A3.y * s3;
    acc.z = A0.z * s0 + A1.z * s1 + A2.z * s2 + A3.z * s3;
    acc.w = A0.w * s0 + A1.w * s1 + A2.w * s2 + A3.w * s3;
    const float inv = 1.0f / den;
    float4 bb = ((const float4*)b1)[lane];
    float vx = acc.x * inv + bb.x, vy = acc.y * inv + bb.y;
    float vz = acc.z * inv + bb.z, vw = acc.w * inv + bb.w;
    vx = vx > 0.f ? vx : 0.f; vy = vy > 0.f ? vy : 0.f;
    vz = vz > 0.f ? vz : 0.f; vw = vw > 0.f ? vw : 0.f;
    ushort4 o = {f2b(vx), f2b(vy), f2b(vz), f2b(vw)};
    ((ushort4*)(x2 + (size_t)n * 256))[lane] = o;
}

// ---------------- layer 2 GEMM via MFMA: h2 = x2 @ W2 (256->32), fused logits ----------------
__global__ __launch_bounds__(256) void gemm2_kernel(const unsigned short* __restrict__ x2,
                                                    const unsigned short* __restrict__ W2T,
                                                    const float* __restrict__ att_src2,
                                                    const float* __restrict__ att_dst2,
                                                    unsigned short* __restrict__ h2,
                                                    float* __restrict__ a_src2,
                                                    float* __restrict__ a_dst2) {
    const int wv = threadIdx.x >> 6;
    const int lane = threadIdx.x & 63;
    const int quad = lane >> 4, c = lane & 15;
    const int base_m = blockIdx.x * 128 + wv * 32;
    f32x4 acc[2][2] = {{{0, 0, 0, 0}, {0, 0, 0, 0}}, {{0, 0, 0, 0}, {0, 0, 0, 0}}};
#pragma unroll
    for (int ks = 0; ks < 8; ks++) {
        bf16x8 b0 = *(const bf16x8*)(W2T + (size_t)c * 256 + ks * 32 + quad * 8);
        bf16x8 b1 = *(const bf16x8*)(W2T + (size_t)(16 + c) * 256 + ks * 32 + quad * 8);
#pragma unroll
        for (int mt = 0; mt < 2; mt++) {
            int row = base_m + mt * 16 + c;
            int rowc = row < N ? row : N - 1;
            bf16x8 a = *(const bf16x8*)(x2 + (size_t)rowc * 256 + ks * 32 + quad * 8);
            acc[mt][0] = __builtin_amdgcn_mfma_f32_16x16x32_bf16(a, b0, acc[mt][0], 0, 0, 0);
            acc[mt][1] = __builtin_amdgcn_mfma_f32_16x16x32_bf16(a, b1, acc[mt][1], 0, 0, 0);
        }
    }
    float as0 = att_src2[c], as1 = att_src2[16 + c];
    float ad0 = att_dst2[c], ad1 = att_dst2[16 + c];
#pragma unroll
    for (int mt = 0; mt < 2; mt++) {
#pragma unroll
        for (int r = 0; r < 4; r++) {
            int row = base_m + mt * 16 + quad * 4 + r;
            float v0 = acc[mt][0][r], v1 = acc[mt][1][r];
            float ps = v0 * as0 + v1 * as1;
            float pd = v0 * ad0 + v1 * ad1;
#pragma unroll
            for (int off = 1; off < 16; off <<= 1) {
                ps += __shfl_xor(ps, off, 64);
                pd += __shfl_xor(pd, off, 64);
            }
            if (row < N) {
                h2[(size_t)row * 32 + c] = f2b(v0);
                h2[(size_t)row * 32 + 16 + c] = f2b(v1);
                if (c == 0) { a_src2[row] = ps; a_dst2[row] = pd; }
            }
        }
    }
}

// ---------------- layer 2 segmented softmax-aggregate: half-wave per node, 4 chains ----------------
#define CH2_UPD(K)                                                       \
    {                                                                    \
        float mn = fmaxf(m##K, al##K);                                   \
        float sc = __expf(m##K - mn);                                    \
        float ea = __expf(al##K - mn);                                   \
        d##K = d##K * sc + ea;                                           \
        A##K = A##K * sc + ea * hv##K;                                   \
        m##K = mn;                                                       \
    }

__global__ __launch_bounds__(256) void seg2_kernel(const int* __restrict__ esrc,
                                                   const int* __restrict__ rofs,
                                                   const float* __restrict__ a_src2,
                                                   const float* __restrict__ a_dst2,
                                                   const unsigned short* __restrict__ h2,
                                                   const float* __restrict__ b2,
                                                   float* __restrict__ v2) {
    const int n = (blockIdx.x * 256 + threadIdx.x) >> 5;
    const int c = threadIdx.x & 31;
    if (n >= N) return;
    const int rs = rofs[n], re = rofs[n + 1];
    const float ad = a_dst2[n];
    float m0 = -1e30f, m1 = -1e30f, m2 = -1e30f, m3 = -1e30f;
    float d0 = 0.f, d1 = 0.f, d2 = 0.f, d3 = 0.f;
    float A0 = 0.f, A1 = 0.f, A2 = 0.f, A3 = 0.f;
    int j = rs;
    for (; j + 4 <= re; j += 4) {
        int s0 = esrc[j], s1 = esrc[j + 1], s2 = esrc[j + 2], s3 = esrc[j + 3];
        float hv0 = b2f(h2[(size_t)s0 * 32 + c]);
        float hv1 = b2f(h2[(size_t)s1 * 32 + c]);
        float hv2 = b2f(h2[(size_t)s2 * 32 + c]);
        float hv3 = b2f(h2[(size_t)s3 * 32 + c]);
        float al0 = lrelu(a_src2[s0] + ad);
        float al1 = lrelu(a_src2[s1] + ad);
        float al2 = lrelu(a_src2[s2] + ad);
        float al3 = lrelu(a_src2[s3] + ad);
        CH2_UPD(0) CH2_UPD(1) CH2_UPD(2) CH2_UPD(3)
    }
    for (; j < re; j++) {
        int s0 = esrc[j];
        float hv0 = b2f(h2[(size_t)s0 * 32 + c]);
        float al0 = lrelu(a_src2[s0] + ad);
        CH2_UPD(0)
    }
    float M = fmaxf(fmaxf(m0, m1), fmaxf(m2, m3));
    float s0 = __expf(m0 - M), s1 = __expf(m1 - M), s2 = __expf(m2 - M), s3 = __expf(m3 - M);
    float den = d0 * s0 + d1 * s1 + d2 * s2 + d3 * s3;
    float acc = A0 * s0 + A1 * s1 + A2 * s2 + A3 * s3;
    v2[(size_t)n * 32 + c] = acc / den + b2[c];
}

// ---------------- final: linear 32->40 ----------------
__global__ __launch_bounds__(256) void final_kernel(const float* __restrict__ v2,
                                                    const float* __restrict__ linW,
                                                    const float* __restrict__ linb,
                                                    float* __restrict__ out) {
    __shared__ float lws[32 * 40];
    __shared__ float vbuf[4][32];
    const int t = threadIdx.x;
    for (int i = t; i < 1280; i += 256) lws[i] = linW[i];
    const int w = t >> 6, lane = t & 63;
    const int n = blockIdx.x * 4 + w;
    if (lane < 32) vbuf[w][lane] = v2[(size_t)n * 32 + lane];
    __syncthreads();
    if (lane < 40) {
        float acc = linb[lane];
#pragma unroll
        for (int c = 0; c < 32; c++) acc += vbuf[w][c] * lws[c * 40 + lane];
        out[(size_t)n * 40 + lane] = acc;
    }
}

extern "C" void kernel_launch(void* const* d_in, const int* in_sizes, int n_in,
                              void* d_out, int out_size, void* d_ws, size_t ws_size,
                              hipStream_t stream) {
    const float* x0       = (const float*)d_in[0];
    const float* W1       = (const float*)d_in[1];
    const float* att_src1 = (const float*)d_in[2];
    const float* att_dst1 = (const float*)d_in[3];
    const float* b1       = (const float*)d_in[4];
    const float* W2       = (const float*)d_in[5];
    const float* att_src2 = (const float*)d_in[6];
    const float* att_dst2 = (const float*)d_in[7];
    const float* b2       = (const float*)d_in[8];
    const float* linW     = (const float*)d_in[9];
    const float* linb     = (const float*)d_in[10];
    const int*   ei       = (const int*)d_in[11];
    float* out = (float*)d_out;
    float* ws  = (float*)d_ws;

    unsigned short* h1  = (unsigned short*)ws;                  // 25.6M bf16
    unsigned short* x2  = (unsigned short*)(ws + 12800000);     // 25.6M bf16
    float* a_src1       = ws + 25600000;                        // 0.8M
    float* a_dst1       = ws + 26400000;                        // 0.8M
    unsigned short* h2  = (unsigned short*)(ws + 27200000);     // 3.2M bf16
    float* v2           = ws + 28800000;                        // 3.2M
    float* a_src2       = ws + 32000000;                        // 0.1M
    float* a_dst2       = ws + 32100000;                        // 0.1M
    unsigned short* W1T = (unsigned short*)(ws + 32200000);     // 32768 bf16
    unsigned short* W2T = (unsigned short*)(ws + 32220000);     // 8192 bf16
    int*   hist         = (int*)(ws + 32230000);                // 0.1M
    int*   rofs         = (int*)(ws + 32330000);                // N+1
    int*   cursor       = (int*)(ws + 32440000);                // 0.1M
    int*   bsum         = (int*)(ws + 32540000);                // 512
    int*   esrc         = (int*)(ws + 32541000);                // 1.1M

    hipMemsetAsync(hist, 0, (size_t)N * 4, stream);

    hist_kernel<<<(ETOT + 255) / 256, 256, 0, stream>>>(ei, hist);
    scan1_kernel<<<NB1, 256, 0, stream>>>(hist, rofs, bsum);
    scan2_kernel<<<1, 512, 0, stream>>>(bsum);
    scan3_kernel<<<NB1, 256, 0, stream>>>(rofs, bsum, cursor);
    scatter_kernel<<<(ETOT + 255) / 256, 256, 0, stream>>>(ei, cursor, esrc);

    w1t_kernel<<<128, 256, 0, stream>>>(W1, W1T);
    w2t_kernel<<<32, 256, 0, stream>>>(W2, W2T);
    gemm1_kernel<<<(N + 127) / 128, 256, 0, stream>>>(x0, W1T, h1);
    att1_kernel<<<N / 4, 256, 0, stream>>>(h1, att_src1, att_dst1, a_src1, a_dst1);
    seg1_kernel<<<N / 4, 256, 0, stream>>>(esrc, rofs, a_src1, a_dst1, h1, b1, x2);
    gemm2_kernel<<<(N + 127) / 128, 256, 0, stream>>>(x2, W2T, att_src2, att_dst2, h2, a_src2, a_dst2);
    seg2_kernel<<<N / 8, 256, 0, stream>>>(esrc, rofs, a_src2, a_dst2, h2, b2, v2);
    final_kernel<<<N / 4, 256, 0, stream>>>(v2, linW, linb, out);
}